// Round 14
// baseline (736.632 us; speedup 1.0000x reference)
//
#include <hip/hip_runtime.h>
#include <hip/hip_cooperative_groups.h>

// GraphSAGE 2-layer + edge scorer, MI355X.
// R14: R13's cooperative mega-kernel, made fail-safe: grid-parametric
// (gridDim.x strides), launch cascade 512 -> 256 -> R12 multi-kernel
// fallback (known-good 231 us). R13 failed because the coop launch was
// rejected (return code unchecked) -- output stayed zero.
// Algorithm in both paths identical to R12: u32 CSR records, atomic-free
// hist, 8-edge-ILP gather1, B-in-regs GEMMs, wp-dot commute, mean@W2n rewrite.

namespace cg = cooperative_groups;

#define NN 50000
#define EM 800000
#define EPOS 200000
#define ENEG 200000
#define NB 196            // coarse buckets: 196*256 >= NN
#define RPB 4096          // records per bin/coarse chunk
#define CBLK 196          // hist chunks: 196*4096 >= EM
#define MTILES 3125       // 50000 / 16 exactly
#define XCONV 6250        // NN*128/4/256

typedef __bf16 bf16;
typedef bf16 bf16x4 __attribute__((ext_vector_type(4)));
typedef bf16 bf16x8 __attribute__((ext_vector_type(8)));
typedef float floatx4 __attribute__((ext_vector_type(4)));

// ---- workspace offsets ----
// int-word offsets:
#define I_BOFF 0             // 512 (entries 0..NB)
#define I_CCUR 512           // 256
#define I_ROW  768           // 50432 -> ends 51200
#define I_CSR  51200         // 800000 -> ends 851200
#define I_HG   851200        // 196*256 -> ends 901376
// byte offsets:
#define B_CREG 3605504       // 800000 * 4B (3.2 MB)
#define B_XB   6805504       // 12.8 MB
#define B_AGG1 19605504      // 12.8 MB
#define B_H1   32405504      // 25.6 MB
#define B_NV   58005504      // 800 KB
#define B_WT1  58805504      // 128 KB
#define B_WT2  58936576      // 128 KB
#define B_P    59067648      // 200 KB
#define B_Q    59268352      // 200 KB

struct BinSmem {
    int hist[NB];
    int cnt2[NB];
    int goff[NB];
    int base[256];
    unsigned sorted[RPB];
    unsigned char sbkt[RPB];
};  // 23856 B

// ===================== cooperative mega-kernel =====================
__global__ __launch_bounds__(256, 2) void mega_kernel(
    const float* __restrict__ x, const int* __restrict__ msrc,
    const int* __restrict__ mdst, const int* __restrict__ psrc,
    const int* __restrict__ pdst, const int* __restrict__ nsrc,
    const int* __restrict__ ndst, const float* __restrict__ W1s,
    const float* __restrict__ W1n, const float* __restrict__ b1,
    const float* __restrict__ W2s, const float* __restrict__ W2n,
    const float* __restrict__ b2, const float* __restrict__ wp,
    const float* __restrict__ bp, float* __restrict__ out,
    bf16* __restrict__ xb, bf16* __restrict__ agg1b, bf16* __restrict__ h1b,
    float4* __restrict__ nodev, bf16* __restrict__ Wt1, bf16* __restrict__ Wt2,
    float* __restrict__ p, float* __restrict__ q,
    int* __restrict__ boff, int* __restrict__ ccur,
    int* __restrict__ rowstart, int* __restrict__ csr,
    int* __restrict__ hgrid, unsigned* __restrict__ creg) {
    cg::grid_group gg = cg::this_grid();
    __shared__ alignas(16) unsigned char SM[24576];
    int t = threadIdx.x;
    int G = gridDim.x;

    // ---- P0: x->bf16, weights->Wt1/Wt2, coarse hist ----
    for (int vb = blockIdx.x; vb < XCONV + 256 + CBLK; vb += G) {
        if (vb < XCONV) {
            int i = vb * 256 + t;
            float4 v = ((const float4*)x)[i];
            bf16x4 o;
            o[0] = (bf16)v.x; o[1] = (bf16)v.y; o[2] = (bf16)v.z; o[3] = (bf16)v.w;
            *(bf16x4*)(xb + (size_t)i * 4) = o;
        } else if (vb < XCONV + 256) {
            int i = (vb - XCONV) * 256 + t;
            int n = i >> 8, k = i & 255;
            float w1 = (k < 128) ? W1s[k * 256 + n] : W1n[(k - 128) * 256 + n];
            Wt1[i] = (bf16)w1;
            float w2 = (n < 128) ? W2n[k * 128 + n] : W2s[k * 128 + (n - 128)];
            Wt2[i] = (bf16)w2;
        } else {
            int* h = (int*)SM;
            int cb = vb - (XCONV + 256);
            h[t] = 0;
            __syncthreads();
            int e0 = cb * RPB;
            int nrec = EM - e0; if (nrec > RPB) nrec = RPB;
            for (int j = t; j < nrec; j += 256) atomicAdd(&h[mdst[e0 + j] >> 8], 1);
            __syncthreads();
            hgrid[cb * 256 + t] = h[t];
            __syncthreads();
        }
    }
    gg.sync();

    // ---- P1: column-sum + exclusive scan -> boff, ccur (block 0) ----
    if (blockIdx.x == 0) {
        int* s = (int*)SM;
        int sum = 0;
        for (int cb = 0; cb < CBLK; ++cb) sum += hgrid[cb * 256 + t];
        s[t] = sum;
        __syncthreads();
        for (int o = 1; o < 256; o <<= 1) {
            int u = (t >= o) ? s[t - o] : 0;
            __syncthreads();
            s[t] += u;
            __syncthreads();
        }
        int excl = (t == 0) ? 0 : s[t - 1];
        if (t <= NB) boff[t] = (t == NB) ? EM : excl;
        if (t < NB) ccur[t] = excl;
    }
    gg.sync();

    // ---- P2: bin ----
    {
        BinSmem* bs = (BinSmem*)SM;
        for (int vb = blockIdx.x; vb < CBLK; vb += G) {
            int e0 = vb * RPB;
            int nrec = EM - e0; if (nrec > RPB) nrec = RPB;
            for (int i = t; i < NB; i += 256) { bs->hist[i] = 0; bs->cnt2[i] = 0; }
            __syncthreads();
            int myb[16];
            unsigned myrec[16];
#pragma unroll
            for (int j = 0; j < 16; ++j) {
                int idx = j * 256 + t;
                if (idx < nrec) {
                    int s = msrc[e0 + idx], d = mdst[e0 + idx];
                    myb[j] = d >> 8;
                    myrec[j] = ((unsigned)(d & 255) << 16) | (unsigned)s;
                    atomicAdd(&bs->hist[myb[j]], 1);
                } else myb[j] = -1;
            }
            __syncthreads();
            bs->base[t] = (t < NB) ? bs->hist[t] : 0;
            __syncthreads();
            for (int o = 1; o < 256; o <<= 1) {
                int u = (t >= o) ? bs->base[t - o] : 0;
                __syncthreads();
                bs->base[t] += u;
                __syncthreads();
            }
            if (t < NB && bs->hist[t] > 0) bs->goff[t] = atomicAdd(&ccur[t], bs->hist[t]);
#pragma unroll
            for (int j = 0; j < 16; ++j) {
                if (myb[j] >= 0) {
                    int rk = atomicAdd(&bs->cnt2[myb[j]], 1);
                    int slot = bs->base[myb[j]] - bs->hist[myb[j]] + rk;
                    bs->sorted[slot] = myrec[j];
                    bs->sbkt[slot] = (unsigned char)myb[j];
                }
            }
            __syncthreads();
#pragma unroll
            for (int j = 0; j < 16; ++j) {
                int idx = j * 256 + t;
                if (idx < nrec) {
                    int b = bs->sbkt[idx];
                    int exb = bs->base[b] - bs->hist[b];
                    creg[(size_t)bs->goff[b] + (idx - exb)] = bs->sorted[idx];
                }
            }
            __syncthreads();
        }
    }
    gg.sync();

    // ---- P3: binsort ----
    {
        int* lcnt = (int*)SM;
        int* sc = lcnt + 256;
        int* lcur = sc + 256;
        for (int vb = blockIdx.x; vb < NB; vb += G) {
            int beg = boff[vb], end = boff[vb + 1];
            lcnt[t] = 0;
            __syncthreads();
            for (int i = beg + t; i < end; i += 256)
                atomicAdd(&lcnt[(int)(creg[i] >> 16) & 255], 1);
            __syncthreads();
            sc[t] = lcnt[t];
            __syncthreads();
            for (int o = 1; o < 256; o <<= 1) {
                int u = (t >= o) ? sc[t - o] : 0;
                __syncthreads();
                sc[t] += u;
                __syncthreads();
            }
            int excl = beg + sc[t] - lcnt[t];
            int node = vb * 256 + t;
            if (node < NN) rowstart[node] = excl;
            if (vb == NB - 1 && t == 0) rowstart[NN] = EM;
            lcur[t] = excl;
            __syncthreads();
            for (int i = beg + t; i < end; i += 256) {
                unsigned rec = creg[i];
                int pos = atomicAdd(&lcur[(int)(rec >> 16) & 255], 1);
                csr[pos] = (int)(rec & 0xffffu);
            }
            __syncthreads();
        }
    }
    gg.sync();

    // ---- P4: gather1 ----
    {
        int gw = blockIdx.x * 4 + (t >> 6);
        int lane = t & 63;
        int q4 = lane >> 4, r = lane & 15;
        int c = r * 8;
        for (int node = gw; node < NN; node += G * 4) {
            int beg = rowstart[node], end = rowstart[node + 1];
            float acc[8] = {0.f, 0.f, 0.f, 0.f, 0.f, 0.f, 0.f, 0.f};
            float acc2[8] = {0.f, 0.f, 0.f, 0.f, 0.f, 0.f, 0.f, 0.f};
            int i = beg + q4;
            for (; i + 4 < end; i += 8) {
                int s0 = csr[i], s1 = csr[i + 4];
                bf16x8 v0 = *(const bf16x8*)(xb + (size_t)s0 * 128 + c);
                bf16x8 v1 = *(const bf16x8*)(xb + (size_t)s1 * 128 + c);
#pragma unroll
                for (int u = 0; u < 8; ++u) {
                    acc[u] += (float)v0[u];
                    acc2[u] += (float)v1[u];
                }
            }
            if (i < end) {
                int s0 = csr[i];
                bf16x8 v0 = *(const bf16x8*)(xb + (size_t)s0 * 128 + c);
#pragma unroll
                for (int u = 0; u < 8; ++u) acc[u] += (float)v0[u];
            }
#pragma unroll
            for (int u = 0; u < 8; ++u) acc[u] += acc2[u];
#pragma unroll
            for (int m = 16; m <= 32; m <<= 1)
#pragma unroll
                for (int u = 0; u < 8; ++u) acc[u] += __shfl_xor(acc[u], m);
            if (q4 == 0) {
                int deg = end - beg;
                float inv = 1.0f / (float)(deg > 0 ? deg : 1);
                bf16x8 o;
#pragma unroll
                for (int u = 0; u < 8; ++u) o[u] = (bf16)(acc[u] * inv);
                *(bf16x8*)(agg1b + (size_t)node * 128 + c) = o;
            }
        }
    }
    gg.sync();

    // ---- P5: gemm1 ----
    {
        int w = t >> 6;
        int lane = t & 63;
        int r = lane & 15, quad = lane >> 4;
        int colbase = w * 64;
        bf16x8 bfr[4][8];
#pragma unroll
        for (int tt = 0; tt < 4; ++tt)
#pragma unroll
            for (int kk = 0; kk < 8; ++kk)
                bfr[tt][kk] = *(const bf16x8*)(Wt1 + (size_t)(colbase + tt * 16 + r) * 256
                                               + kk * 32 + quad * 8);
        float bb[4];
#pragma unroll
        for (int tt = 0; tt < 4; ++tt) bb[tt] = b1[colbase + tt * 16 + r];

        for (int tile = blockIdx.x; tile < MTILES; tile += G) {
            int m0 = tile * 16;
            int row = m0 + r;
            bf16x8 a[8];
#pragma unroll
            for (int kk = 0; kk < 4; ++kk)
                a[kk] = *(const bf16x8*)(xb + (size_t)row * 128 + kk * 32 + quad * 8);
#pragma unroll
            for (int kk = 4; kk < 8; ++kk)
                a[kk] = *(const bf16x8*)(agg1b + (size_t)row * 128 + (kk - 4) * 32 + quad * 8);
            floatx4 acc[4];
#pragma unroll
            for (int tt = 0; tt < 4; ++tt) acc[tt] = (floatx4){0.f, 0.f, 0.f, 0.f};
#pragma unroll
            for (int kk = 0; kk < 8; ++kk)
#pragma unroll
                for (int tt = 0; tt < 4; ++tt)
                    acc[tt] = __builtin_amdgcn_mfma_f32_16x16x32_bf16(a[kk], bfr[tt][kk],
                                                                      acc[tt], 0, 0, 0);
            int mb = m0 + quad * 4;
#pragma unroll
            for (int tt = 0; tt < 4; ++tt) {
                int col = colbase + tt * 16 + r;
#pragma unroll
                for (int rr = 0; rr < 4; ++rr) {
                    float v = acc[tt][rr] + bb[tt];
                    v = v > 0.f ? v : 0.f;
                    h1b[(size_t)(mb + rr) * 256 + col] = (bf16)v;
                }
            }
        }
    }
    gg.sync();

    // ---- P6: gemm2 -> nodev ----
    {
        float* lp = (float*)SM;
        float* lq = lp + 64;
        int w = t >> 6;
        int lane = t & 63;
        int r = lane & 15, quad = lane >> 4;
        int colbase = w * 64;
        bf16x8 bfr[4][8];
#pragma unroll
        for (int tt = 0; tt < 4; ++tt)
#pragma unroll
            for (int kk = 0; kk < 8; ++kk)
                bfr[tt][kk] = *(const bf16x8*)(Wt2 + (size_t)(colbase + tt * 16 + r) * 256
                                               + kk * 32 + quad * 8);
        float bb[4], wA[4], wB[4];
#pragma unroll
        for (int tt = 0; tt < 4; ++tt) {
            int col = colbase + tt * 16 + r;
            if (w < 2) {
                bb[tt] = 0.f;
                wA[tt] = wp[col];
                wB[tt] = wp[128 + col];
            } else {
                int c2 = col - 128;
                bb[tt] = b2[c2];
                wA[tt] = wp[c2];
                wB[tt] = wp[128 + c2];
            }
        }
        for (int tile = blockIdx.x; tile < MTILES; tile += G) {
            int m0 = tile * 16;
            int row = m0 + r;
            bf16x8 a[8];
#pragma unroll
            for (int kk = 0; kk < 8; ++kk)
                a[kk] = *(const bf16x8*)(h1b + (size_t)row * 256 + kk * 32 + quad * 8);
            floatx4 acc[4];
#pragma unroll
            for (int tt = 0; tt < 4; ++tt) acc[tt] = (floatx4){0.f, 0.f, 0.f, 0.f};
#pragma unroll
            for (int kk = 0; kk < 8; ++kk)
#pragma unroll
                for (int tt = 0; tt < 4; ++tt)
                    acc[tt] = __builtin_amdgcn_mfma_f32_16x16x32_bf16(a[kk], bfr[tt][kk],
                                                                      acc[tt], 0, 0, 0);
            float pacc[4], qacc[4];
#pragma unroll
            for (int rr = 0; rr < 4; ++rr) {
                float pr = 0.f, qr = 0.f;
#pragma unroll
                for (int tt = 0; tt < 4; ++tt) {
                    float v = acc[tt][rr] + bb[tt];
                    pr += v * wA[tt];
                    qr += v * wB[tt];
                }
                pacc[rr] = pr;
                qacc[rr] = qr;
            }
#pragma unroll
            for (int m = 1; m <= 8; m <<= 1) {
#pragma unroll
                for (int rr = 0; rr < 4; ++rr) {
                    pacc[rr] += __shfl_xor(pacc[rr], m);
                    qacc[rr] += __shfl_xor(qacc[rr], m);
                }
            }
            if (r == 0) {
#pragma unroll
                for (int rr = 0; rr < 4; ++rr) {
                    lp[w * 16 + quad * 4 + rr] = pacc[rr];
                    lq[w * 16 + quad * 4 + rr] = qacc[rr];
                }
            }
            __syncthreads();
            if (t < 16) {
                float4 o;
                o.x = lp[t] + lp[16 + t];
                o.y = lq[t] + lq[16 + t];
                o.z = lp[32 + t] + lp[48 + t];
                o.w = lq[32 + t] + lq[48 + t];
                nodev[m0 + t] = o;
            }
            __syncthreads();
        }
    }
    gg.sync();

    // ---- P7: gather2 ----
    {
        int slot = blockIdx.x * 16 + (t >> 4);
        int l = t & 15;
        for (int node = slot; node < NN; node += G * 16) {
            int beg = rowstart[node], end = rowstart[node + 1];
            float pz = 0.f, qz = 0.f;
            for (int i = beg + l; i < end; i += 16) {
                float4 v = nodev[csr[i]];
                pz += v.x;
                qz += v.y;
            }
#pragma unroll
            for (int m = 8; m >= 1; m >>= 1) {
                pz += __shfl_xor(pz, m);
                qz += __shfl_xor(qz, m);
            }
            if (l == 0) {
                int deg = end - beg;
                float inv = 1.0f / (float)(deg > 0 ? deg : 1);
                float4 me = nodev[node];
                p[node] = me.z + pz * inv;
                q[node] = me.w + qz * inv;
            }
        }
    }
    gg.sync();

    // ---- P8: score ----
    {
        float b = bp[0];
        for (int i = blockIdx.x * 256 + t; i < EPOS + ENEG; i += G * 256) {
            if (i < EPOS) {
                out[i] = p[psrc[i]] + q[pdst[i]] + b;
            } else {
                int j = i - EPOS;
                out[i] = p[nsrc[j]] + q[ndst[j]] + b;
            }
        }
    }
}

// ===================== R12 fallback kernels =====================
__global__ __launch_bounds__(256) void convc_kernel(
    const float* __restrict__ x, bf16* __restrict__ xb,
    const float* __restrict__ W1s, const float* __restrict__ W1n,
    const float* __restrict__ W2n, const float* __restrict__ W2s,
    bf16* __restrict__ Wt1, bf16* __restrict__ Wt2,
    const int* __restrict__ mdst, int* __restrict__ hgrid) {
    if (blockIdx.x < XCONV) {
        int i = blockIdx.x * 256 + threadIdx.x;
        float4 v = ((const float4*)x)[i];
        bf16x4 o;
        o[0] = (bf16)v.x; o[1] = (bf16)v.y; o[2] = (bf16)v.z; o[3] = (bf16)v.w;
        *(bf16x4*)(xb + (size_t)i * 4) = o;
    } else if (blockIdx.x < XCONV + 256) {
        int i = (blockIdx.x - XCONV) * 256 + threadIdx.x;
        int n = i >> 8, k = i & 255;
        float w1 = (k < 128) ? W1s[k * 256 + n] : W1n[(k - 128) * 256 + n];
        Wt1[i] = (bf16)w1;
        float w2 = (n < 128) ? W2n[k * 128 + n] : W2s[k * 128 + (n - 128)];
        Wt2[i] = (bf16)w2;
    } else {
        __shared__ int h[256];
        int t = threadIdx.x;
        int cb = blockIdx.x - (XCONV + 256);
        h[t] = 0;
        __syncthreads();
        int e0 = cb * RPB;
        int nrec = EM - e0; if (nrec > RPB) nrec = RPB;
        for (int j = t; j < nrec; j += 256) atomicAdd(&h[mdst[e0 + j] >> 8], 1);
        __syncthreads();
        hgrid[cb * 256 + t] = h[t];
    }
}

__global__ __launch_bounds__(256) void cscan_kernel(const int* __restrict__ hgrid,
                                                    int* __restrict__ boff,
                                                    int* __restrict__ ccur) {
    __shared__ int s[256];
    int t = threadIdx.x;
    int sum = 0;
    for (int cb = 0; cb < CBLK; ++cb) sum += hgrid[cb * 256 + t];
    s[t] = sum;
    __syncthreads();
    for (int o = 1; o < 256; o <<= 1) {
        int u = (t >= o) ? s[t - o] : 0;
        __syncthreads();
        s[t] += u;
        __syncthreads();
    }
    int excl = (t == 0) ? 0 : s[t - 1];
    if (t <= NB) boff[t] = (t == NB) ? EM : excl;
    if (t < NB) ccur[t] = excl;
}

__global__ __launch_bounds__(256) void bin2_kernel(const int* __restrict__ src,
                                                   const int* __restrict__ dst,
                                                   int* __restrict__ ccur,
                                                   unsigned* __restrict__ creg) {
    __shared__ int hist[NB];
    __shared__ int cnt2[NB];
    __shared__ int goff[NB];
    __shared__ int base[256];
    __shared__ unsigned sorted[RPB];
    __shared__ unsigned char sbkt[RPB];
    int t = threadIdx.x;
    int e0 = blockIdx.x * RPB;
    int nrec = EM - e0; if (nrec > RPB) nrec = RPB;

    for (int i = t; i < NB; i += 256) { hist[i] = 0; cnt2[i] = 0; }
    __syncthreads();

    int myb[16];
    unsigned myrec[16];
#pragma unroll
    for (int j = 0; j < 16; ++j) {
        int idx = j * 256 + t;
        if (idx < nrec) {
            int s = src[e0 + idx], d = dst[e0 + idx];
            myb[j] = d >> 8;
            myrec[j] = ((unsigned)(d & 255) << 16) | (unsigned)s;
            atomicAdd(&hist[myb[j]], 1);
        } else myb[j] = -1;
    }
    __syncthreads();

    base[t] = (t < NB) ? hist[t] : 0;
    __syncthreads();
    for (int o = 1; o < 256; o <<= 1) {
        int u = (t >= o) ? base[t - o] : 0;
        __syncthreads();
        base[t] += u;
        __syncthreads();
    }

    if (t < NB && hist[t] > 0) goff[t] = atomicAdd(&ccur[t], hist[t]);
#pragma unroll
    for (int j = 0; j < 16; ++j) {
        if (myb[j] >= 0) {
            int rk = atomicAdd(&cnt2[myb[j]], 1);
            int slot = base[myb[j]] - hist[myb[j]] + rk;
            sorted[slot] = myrec[j];
            sbkt[slot] = (unsigned char)myb[j];
        }
    }
    __syncthreads();

#pragma unroll
    for (int j = 0; j < 16; ++j) {
        int idx = j * 256 + t;
        if (idx < nrec) {
            int b = sbkt[idx];
            int exb = base[b] - hist[b];
            creg[(size_t)goff[b] + (idx - exb)] = sorted[idx];
        }
    }
}

__global__ __launch_bounds__(256) void binsort_kernel(
    const unsigned* __restrict__ creg, const int* __restrict__ boff,
    int* __restrict__ rowstart, int* __restrict__ csr) {
    __shared__ int lcnt[256];
    __shared__ int sc[256];
    __shared__ int lcur[256];
    int b = blockIdx.x, t = threadIdx.x;
    int beg = boff[b], end = boff[b + 1];
    lcnt[t] = 0;
    __syncthreads();
    for (int i = beg + t; i < end; i += 256)
        atomicAdd(&lcnt[(int)(creg[i] >> 16) & 255], 1);
    __syncthreads();
    sc[t] = lcnt[t];
    __syncthreads();
    for (int o = 1; o < 256; o <<= 1) {
        int u = (t >= o) ? sc[t - o] : 0;
        __syncthreads();
        sc[t] += u;
        __syncthreads();
    }
    int excl = beg + sc[t] - lcnt[t];
    int node = b * 256 + t;
    if (node < NN) rowstart[node] = excl;
    if (b == NB - 1 && t == 0) rowstart[NN] = EM;
    lcur[t] = excl;
    __syncthreads();
    for (int i = beg + t; i < end; i += 256) {
        unsigned rec = creg[i];
        int pos = atomicAdd(&lcur[(int)(rec >> 16) & 255], 1);
        csr[pos] = (int)(rec & 0xffffu);
    }
}

__global__ __launch_bounds__(256) void gather1_kernel(const bf16* __restrict__ feat,
                                                      const int* __restrict__ rowstart,
                                                      const int* __restrict__ csr,
                                                      bf16* __restrict__ agg) {
    int node = (blockIdx.x * 256 + threadIdx.x) >> 6;
    if (node >= NN) return;
    int lane = threadIdx.x & 63;
    int q = lane >> 4, r = lane & 15;
    int c = r * 8;
    int beg = rowstart[node], end = rowstart[node + 1];
    float acc[8] = {0.f, 0.f, 0.f, 0.f, 0.f, 0.f, 0.f, 0.f};
    float acc2[8] = {0.f, 0.f, 0.f, 0.f, 0.f, 0.f, 0.f, 0.f};
    int i = beg + q;
    for (; i + 4 < end; i += 8) {
        int s0 = csr[i], s1 = csr[i + 4];
        bf16x8 v0 = *(const bf16x8*)(feat + (size_t)s0 * 128 + c);
        bf16x8 v1 = *(const bf16x8*)(feat + (size_t)s1 * 128 + c);
#pragma unroll
        for (int u = 0; u < 8; ++u) {
            acc[u] += (float)v0[u];
            acc2[u] += (float)v1[u];
        }
    }
    if (i < end) {
        int s0 = csr[i];
        bf16x8 v0 = *(const bf16x8*)(feat + (size_t)s0 * 128 + c);
#pragma unroll
        for (int u = 0; u < 8; ++u) acc[u] += (float)v0[u];
    }
#pragma unroll
    for (int u = 0; u < 8; ++u) acc[u] += acc2[u];
#pragma unroll
    for (int m = 16; m <= 32; m <<= 1)
#pragma unroll
        for (int u = 0; u < 8; ++u) acc[u] += __shfl_xor(acc[u], m);
    if (q == 0) {
        int deg = end - beg;
        float inv = 1.0f / (float)(deg > 0 ? deg : 1);
        bf16x8 o;
#pragma unroll
        for (int u = 0; u < 8; ++u) o[u] = (bf16)(acc[u] * inv);
        *(bf16x8*)(agg + (size_t)node * 128 + c) = o;
    }
}

__global__ __launch_bounds__(256) void gemm1_kernel(
    const bf16* __restrict__ xb, const bf16* __restrict__ aggb,
    const bf16* __restrict__ Wt, const float* __restrict__ b1,
    bf16* __restrict__ h1b) {
    int w = threadIdx.x >> 6;
    int lane = threadIdx.x & 63;
    int r = lane & 15, quad = lane >> 4;
    int colbase = w * 64;

    bf16x8 bfr[4][8];
#pragma unroll
    for (int t = 0; t < 4; ++t)
#pragma unroll
        for (int kk = 0; kk < 8; ++kk)
            bfr[t][kk] = *(const bf16x8*)(Wt + (size_t)(colbase + t * 16 + r) * 256
                                          + kk * 32 + quad * 8);
    float bb[4];
#pragma unroll
    for (int t = 0; t < 4; ++t) bb[t] = b1[colbase + t * 16 + r];

    for (int tile = blockIdx.x; tile < MTILES; tile += 512) {
        int m0 = tile * 16;
        int row = m0 + r;
        bf16x8 a[8];
#pragma unroll
        for (int kk = 0; kk < 4; ++kk)
            a[kk] = *(const bf16x8*)(xb + (size_t)row * 128 + kk * 32 + quad * 8);
#pragma unroll
        for (int kk = 4; kk < 8; ++kk)
            a[kk] = *(const bf16x8*)(aggb + (size_t)row * 128 + (kk - 4) * 32 + quad * 8);
        floatx4 acc[4];
#pragma unroll
        for (int t = 0; t < 4; ++t) acc[t] = (floatx4){0.f, 0.f, 0.f, 0.f};
#pragma unroll
        for (int kk = 0; kk < 8; ++kk)
#pragma unroll
            for (int t = 0; t < 4; ++t)
                acc[t] = __builtin_amdgcn_mfma_f32_16x16x32_bf16(a[kk], bfr[t][kk],
                                                                 acc[t], 0, 0, 0);
        int mb = m0 + quad * 4;
#pragma unroll
        for (int t = 0; t < 4; ++t) {
            int col = colbase + t * 16 + r;
#pragma unroll
            for (int rr = 0; rr < 4; ++rr) {
                float v = acc[t][rr] + bb[t];
                v = v > 0.f ? v : 0.f;
                h1b[(size_t)(mb + rr) * 256 + col] = (bf16)v;
            }
        }
    }
}

__global__ __launch_bounds__(256) void gemm2_kernel(
    const bf16* __restrict__ h1b, const bf16* __restrict__ Wt,
    const float* __restrict__ b2, const float* __restrict__ wp,
    float4* __restrict__ nodev) {
    __shared__ float lp[4][16];
    __shared__ float lq[4][16];
    int w = threadIdx.x >> 6;
    int lane = threadIdx.x & 63;
    int r = lane & 15, quad = lane >> 4;
    int colbase = w * 64;

    bf16x8 bfr[4][8];
#pragma unroll
    for (int t = 0; t < 4; ++t)
#pragma unroll
        for (int kk = 0; kk < 8; ++kk)
            bfr[t][kk] = *(const bf16x8*)(Wt + (size_t)(colbase + t * 16 + r) * 256
                                          + kk * 32 + quad * 8);
    float bb[4], wA[4], wB[4];
#pragma unroll
    for (int t = 0; t < 4; ++t) {
        int col = colbase + t * 16 + r;
        if (w < 2) {
            bb[t] = 0.f;
            wA[t] = wp[col];
            wB[t] = wp[128 + col];
        } else {
            int c2 = col - 128;
            bb[t] = b2[c2];
            wA[t] = wp[c2];
            wB[t] = wp[128 + c2];
        }
    }

    for (int tile = blockIdx.x; tile < MTILES; tile += 512) {
        int m0 = tile * 16;
        int row = m0 + r;
        bf16x8 a[8];
#pragma unroll
        for (int kk = 0; kk < 8; ++kk)
            a[kk] = *(const bf16x8*)(h1b + (size_t)row * 256 + kk * 32 + quad * 8);
        floatx4 acc[4];
#pragma unroll
        for (int t = 0; t < 4; ++t) acc[t] = (floatx4){0.f, 0.f, 0.f, 0.f};
#pragma unroll
        for (int kk = 0; kk < 8; ++kk)
#pragma unroll
            for (int t = 0; t < 4; ++t)
                acc[t] = __builtin_amdgcn_mfma_f32_16x16x32_bf16(a[kk], bfr[t][kk],
                                                                 acc[t], 0, 0, 0);
        float pacc[4], qacc[4];
#pragma unroll
        for (int rr = 0; rr < 4; ++rr) {
            float pr = 0.f, qr = 0.f;
#pragma unroll
            for (int t = 0; t < 4; ++t) {
                float v = acc[t][rr] + bb[t];
                pr += v * wA[t];
                qr += v * wB[t];
            }
            pacc[rr] = pr;
            qacc[rr] = qr;
        }
#pragma unroll
        for (int m = 1; m <= 8; m <<= 1) {
#pragma unroll
            for (int rr = 0; rr < 4; ++rr) {
                pacc[rr] += __shfl_xor(pacc[rr], m);
                qacc[rr] += __shfl_xor(qacc[rr], m);
            }
        }
        if (r == 0) {
#pragma unroll
            for (int rr = 0; rr < 4; ++rr) {
                lp[w][quad * 4 + rr] = pacc[rr];
                lq[w][quad * 4 + rr] = qacc[rr];
            }
        }
        __syncthreads();
        if (threadIdx.x < 16) {
            int rw = threadIdx.x;
            float4 o;
            o.x = lp[0][rw] + lp[1][rw];
            o.y = lq[0][rw] + lq[1][rw];
            o.z = lp[2][rw] + lp[3][rw];
            o.w = lq[2][rw] + lq[3][rw];
            nodev[m0 + rw] = o;
        }
        __syncthreads();
    }
}

__global__ __launch_bounds__(256) void gather2_kernel(
    const float4* __restrict__ nodev, const int* __restrict__ rowstart,
    const int* __restrict__ csr, float* __restrict__ p, float* __restrict__ q) {
    int t = threadIdx.x;
    int node = blockIdx.x * 16 + (t >> 4);
    if (node >= NN) return;
    int l = t & 15;
    int beg = rowstart[node], end = rowstart[node + 1];
    float pz = 0.f, qz = 0.f;
    for (int i = beg + l; i < end; i += 16) {
        float4 v = nodev[csr[i]];
        pz += v.x;
        qz += v.y;
    }
#pragma unroll
    for (int m = 8; m >= 1; m >>= 1) {
        pz += __shfl_xor(pz, m);
        qz += __shfl_xor(qz, m);
    }
    if (l == 0) {
        int deg = end - beg;
        float inv = 1.0f / (float)(deg > 0 ? deg : 1);
        float4 me = nodev[node];
        p[node] = me.z + pz * inv;
        q[node] = me.w + qz * inv;
    }
}

__global__ __launch_bounds__(256) void score_kernel(
    const int* __restrict__ psrc, const int* __restrict__ pdst,
    const int* __restrict__ nsrc, const int* __restrict__ ndst,
    const float* __restrict__ p, const float* __restrict__ q,
    const float* __restrict__ bp, float* __restrict__ out) {
    int i = blockIdx.x * blockDim.x + threadIdx.x;
    float b = bp[0];
    if (i < EPOS) {
        out[i] = p[psrc[i]] + q[pdst[i]] + b;
    } else if (i < EPOS + ENEG) {
        int j = i - EPOS;
        out[i] = p[nsrc[j]] + q[ndst[j]] + b;
    }
}

extern "C" void kernel_launch(void* const* d_in, const int* in_sizes, int n_in,
                              void* d_out, int out_size, void* d_ws, size_t ws_size,
                              hipStream_t stream) {
    const float* x    = (const float*)d_in[0];
    const int*   msrc = (const int*)d_in[1];
    const int*   mdst = (const int*)d_in[2];
    const int*   psrc = (const int*)d_in[3];
    const int*   pdst = (const int*)d_in[4];
    const int*   nsrc = (const int*)d_in[5];
    const int*   ndst = (const int*)d_in[6];
    const float* W1s  = (const float*)d_in[7];
    const float* W1n  = (const float*)d_in[8];
    const float* b1   = (const float*)d_in[9];
    const float* W2s  = (const float*)d_in[10];
    const float* W2n  = (const float*)d_in[11];
    const float* b2   = (const float*)d_in[12];
    const float* wp   = (const float*)d_in[13];
    const float* bp   = (const float*)d_in[14];

    char* ws = (char*)d_ws;
    int*   boff     = (int*)ws + I_BOFF;
    int*   ccur     = (int*)ws + I_CCUR;
    int*   rowstart = (int*)ws + I_ROW;
    int*   csr      = (int*)ws + I_CSR;
    int*   hgrid    = (int*)ws + I_HG;
    unsigned* creg  = (unsigned*)(ws + B_CREG);
    bf16*  xb    = (bf16*)(ws + B_XB);
    bf16*  agg1b = (bf16*)(ws + B_AGG1);
    bf16*  h1b   = (bf16*)(ws + B_H1);
    float4* nodev = (float4*)(ws + B_NV);
    bf16*  Wt1   = (bf16*)(ws + B_WT1);
    bf16*  Wt2   = (bf16*)(ws + B_WT2);
    float* p     = (float*)(ws + B_P);
    float* q     = (float*)(ws + B_Q);
    float* out   = (float*)d_out;

    void* args[] = {
        (void*)&x, (void*)&msrc, (void*)&mdst, (void*)&psrc, (void*)&pdst,
        (void*)&nsrc, (void*)&ndst, (void*)&W1s, (void*)&W1n, (void*)&b1,
        (void*)&W2s, (void*)&W2n, (void*)&b2, (void*)&wp, (void*)&bp,
        (void*)&out, (void*)&xb, (void*)&agg1b, (void*)&h1b, (void*)&nodev,
        (void*)&Wt1, (void*)&Wt2, (void*)&p, (void*)&q, (void*)&boff,
        (void*)&ccur, (void*)&rowstart, (void*)&csr, (void*)&hgrid, (void*)&creg
    };

    hipError_t err = hipLaunchCooperativeKernel((const void*)mega_kernel,
                                                dim3(512), dim3(256), args, 0, stream);
    if (err != hipSuccess) {
        (void)hipGetLastError();
        err = hipLaunchCooperativeKernel((const void*)mega_kernel,
                                         dim3(256), dim3(256), args, 0, stream);
    }
    if (err != hipSuccess) {
        (void)hipGetLastError();
        // R12 multi-kernel fallback (known-good, ~232 us)
        convc_kernel<<<XCONV + 256 + CBLK, 256, 0, stream>>>(
            x, xb, W1s, W1n, W2n, W2s, Wt1, Wt2, mdst, hgrid);
        cscan_kernel<<<1, 256, 0, stream>>>(hgrid, boff, ccur);
        bin2_kernel<<<(EM + RPB - 1) / RPB, 256, 0, stream>>>(msrc, mdst, ccur, creg);
        binsort_kernel<<<NB, 256, 0, stream>>>(creg, boff, rowstart, csr);
        gather1_kernel<<<(NN + 3) / 4, 256, 0, stream>>>(xb, rowstart, csr, agg1b);
        gemm1_kernel<<<512, 256, 0, stream>>>(xb, agg1b, Wt1, b1, h1b);
        gemm2_kernel<<<512, 256, 0, stream>>>(h1b, Wt2, b2, wp, nodev);
        gather2_kernel<<<(NN + 15) / 16, 256, 0, stream>>>(nodev, rowstart, csr, p, q);
        score_kernel<<<(EPOS + ENEG + 255) / 256, 256, 0, stream>>>(
            psrc, pdst, nsrc, ndst, p, q, bp, out);
    }
}

// Round 15
// 233.229 us; speedup vs baseline: 3.1584x; 3.1584x over previous
//
#include <hip/hip_runtime.h>

// GraphSAGE 2-layer + edge scorer, MI355X.
// R15: cooperative mega-kernel REVERTED (618 us: grid-syncs + worst-phase
// occupancy; disproved the launch-overhead theory). Back to R12 multi-kernel
// + ONE traffic fusion: gemm1+gemm2 fused through LDS (16x256 h1 tile stays
// in LDS, +8 pad -> 2-way bank aliasing = free). Kills the 51 MB h1 HBM
// round-trip + 1 launch. Wt2 B-frags re-read per tile (L1/L2-hot slice).
// Kept: u32 CSR records, atomic-free hist, 8-edge-ILP gather1, Wt1 B-in-regs,
// wp-dot commute (scalar gather2), mean(h1[src])@W2n == mean((h1@W2n)[src]).

#define NN 50000
#define EM 800000
#define EPOS 200000
#define ENEG 200000
#define NB 196            // coarse buckets: 196*256 >= NN
#define RPB 4096          // records per bin/coarse chunk
#define CBLK 196          // hist chunks: 196*4096 >= EM
#define MTILES 3125       // 50000 / 16 exactly
#define GEMM_GRID 512
#define XCONV 6250        // NN*128/4/256

typedef __bf16 bf16;
typedef bf16 bf16x4 __attribute__((ext_vector_type(4)));
typedef bf16 bf16x8 __attribute__((ext_vector_type(8)));
typedef float floatx4 __attribute__((ext_vector_type(4)));

// ---- workspace offsets ----
// int-word offsets:
#define I_BOFF 0             // 512 (entries 0..NB)
#define I_CCUR 512           // 256
#define I_ROW  768           // 50432 -> ends 51200
#define I_CSR  51200         // 800000 -> ends 851200
#define I_HG   851200        // 196*256 -> ends 901376
// byte offsets:
#define B_CREG 3605504       // 800000 * 4B (3.2 MB)
#define B_XB   6805504       // 12.8 MB
#define B_AGG1 19605504      // 12.8 MB
#define B_NV   32405504      // 800 KB
#define B_WT1  33205504      // 128 KB
#define B_WT2  33336576      // 128 KB
#define B_P    33467648      // 200 KB
#define B_Q    33668352      // 200 KB
// end ~33.9 MB

// fused conversions + atomic-free coarse histogram.
__global__ __launch_bounds__(256) void convc_kernel(
    const float* __restrict__ x, bf16* __restrict__ xb,
    const float* __restrict__ W1s, const float* __restrict__ W1n,
    const float* __restrict__ W2n, const float* __restrict__ W2s,
    bf16* __restrict__ Wt1, bf16* __restrict__ Wt2,
    const int* __restrict__ mdst, int* __restrict__ hgrid) {
    if (blockIdx.x < XCONV) {
        int i = blockIdx.x * 256 + threadIdx.x;
        float4 v = ((const float4*)x)[i];
        bf16x4 o;
        o[0] = (bf16)v.x; o[1] = (bf16)v.y; o[2] = (bf16)v.z; o[3] = (bf16)v.w;
        *(bf16x4*)(xb + (size_t)i * 4) = o;
    } else if (blockIdx.x < XCONV + 256) {
        int i = (blockIdx.x - XCONV) * 256 + threadIdx.x;
        int n = i >> 8, k = i & 255;
        float w1 = (k < 128) ? W1s[k * 256 + n] : W1n[(k - 128) * 256 + n];
        Wt1[i] = (bf16)w1;
        float w2 = (n < 128) ? W2n[k * 128 + n] : W2s[k * 128 + (n - 128)];
        Wt2[i] = (bf16)w2;
    } else {
        __shared__ int h[256];
        int t = threadIdx.x;
        int cb = blockIdx.x - (XCONV + 256);
        h[t] = 0;
        __syncthreads();
        int e0 = cb * RPB;
        int nrec = EM - e0; if (nrec > RPB) nrec = RPB;
        for (int j = t; j < nrec; j += 256) atomicAdd(&h[mdst[e0 + j] >> 8], 1);
        __syncthreads();
        hgrid[cb * 256 + t] = h[t];
    }
}

__global__ __launch_bounds__(256) void cscan_kernel(const int* __restrict__ hgrid,
                                                    int* __restrict__ boff,
                                                    int* __restrict__ ccur) {
    __shared__ int s[256];
    int t = threadIdx.x;
    int sum = 0;
    for (int cb = 0; cb < CBLK; ++cb) sum += hgrid[cb * 256 + t];
    s[t] = sum;
    __syncthreads();
    for (int o = 1; o < 256; o <<= 1) {
        int u = (t >= o) ? s[t - o] : 0;
        __syncthreads();
        s[t] += u;
        __syncthreads();
    }
    int excl = (t == 0) ? 0 : s[t - 1];
    if (t <= NB) boff[t] = (t == NB) ? EM : excl;
    if (t < NB) ccur[t] = excl;
}

__global__ __launch_bounds__(256) void bin2_kernel(const int* __restrict__ src,
                                                   const int* __restrict__ dst,
                                                   int* __restrict__ ccur,
                                                   unsigned* __restrict__ creg) {
    __shared__ int hist[NB];
    __shared__ int cnt2[NB];
    __shared__ int goff[NB];
    __shared__ int base[256];
    __shared__ unsigned sorted[RPB];
    __shared__ unsigned char sbkt[RPB];
    int t = threadIdx.x;
    int e0 = blockIdx.x * RPB;
    int nrec = EM - e0; if (nrec > RPB) nrec = RPB;

    for (int i = t; i < NB; i += 256) { hist[i] = 0; cnt2[i] = 0; }
    __syncthreads();

    int myb[16];
    unsigned myrec[16];
#pragma unroll
    for (int j = 0; j < 16; ++j) {
        int idx = j * 256 + t;
        if (idx < nrec) {
            int s = src[e0 + idx], d = dst[e0 + idx];
            myb[j] = d >> 8;
            myrec[j] = ((unsigned)(d & 255) << 16) | (unsigned)s;
            atomicAdd(&hist[myb[j]], 1);
        } else myb[j] = -1;
    }
    __syncthreads();

    base[t] = (t < NB) ? hist[t] : 0;
    __syncthreads();
    for (int o = 1; o < 256; o <<= 1) {
        int u = (t >= o) ? base[t - o] : 0;
        __syncthreads();
        base[t] += u;
        __syncthreads();
    }

    if (t < NB && hist[t] > 0) goff[t] = atomicAdd(&ccur[t], hist[t]);
#pragma unroll
    for (int j = 0; j < 16; ++j) {
        if (myb[j] >= 0) {
            int rk = atomicAdd(&cnt2[myb[j]], 1);
            int slot = base[myb[j]] - hist[myb[j]] + rk;
            sorted[slot] = myrec[j];
            sbkt[slot] = (unsigned char)myb[j];
        }
    }
    __syncthreads();

#pragma unroll
    for (int j = 0; j < 16; ++j) {
        int idx = j * 256 + t;
        if (idx < nrec) {
            int b = sbkt[idx];
            int exb = base[b] - hist[b];
            creg[(size_t)goff[b] + (idx - exb)] = sorted[idx];
        }
    }
}

__global__ __launch_bounds__(256) void binsort_kernel(
    const unsigned* __restrict__ creg, const int* __restrict__ boff,
    int* __restrict__ rowstart, int* __restrict__ csr) {
    __shared__ int lcnt[256];
    __shared__ int sc[256];
    __shared__ int lcur[256];
    int b = blockIdx.x, t = threadIdx.x;
    int beg = boff[b], end = boff[b + 1];
    lcnt[t] = 0;
    __syncthreads();
    for (int i = beg + t; i < end; i += 256)
        atomicAdd(&lcnt[(int)(creg[i] >> 16) & 255], 1);
    __syncthreads();
    sc[t] = lcnt[t];
    __syncthreads();
    for (int o = 1; o < 256; o <<= 1) {
        int u = (t >= o) ? sc[t - o] : 0;
        __syncthreads();
        sc[t] += u;
        __syncthreads();
    }
    int excl = beg + sc[t] - lcnt[t];
    int node = b * 256 + t;
    if (node < NN) rowstart[node] = excl;
    if (b == NB - 1 && t == 0) rowstart[NN] = EM;
    lcur[t] = excl;
    __syncthreads();
    for (int i = beg + t; i < end; i += 256) {
        unsigned rec = creg[i];
        int pos = atomicAdd(&lcur[(int)(rec >> 16) & 255], 1);
        csr[pos] = (int)(rec & 0xffffu);
    }
}

// one wave per node, 8 edges in flight (2 independent chains per quad-lane).
__global__ __launch_bounds__(256) void gather1_kernel(const bf16* __restrict__ feat,
                                                      const int* __restrict__ rowstart,
                                                      const int* __restrict__ csr,
                                                      bf16* __restrict__ agg) {
    int node = (blockIdx.x * 256 + threadIdx.x) >> 6;
    if (node >= NN) return;
    int lane = threadIdx.x & 63;
    int q = lane >> 4, r = lane & 15;
    int c = r * 8;
    int beg = rowstart[node], end = rowstart[node + 1];
    float acc[8] = {0.f, 0.f, 0.f, 0.f, 0.f, 0.f, 0.f, 0.f};
    float acc2[8] = {0.f, 0.f, 0.f, 0.f, 0.f, 0.f, 0.f, 0.f};
    int i = beg + q;
    for (; i + 4 < end; i += 8) {
        int s0 = csr[i], s1 = csr[i + 4];
        bf16x8 v0 = *(const bf16x8*)(feat + (size_t)s0 * 128 + c);
        bf16x8 v1 = *(const bf16x8*)(feat + (size_t)s1 * 128 + c);
#pragma unroll
        for (int u = 0; u < 8; ++u) {
            acc[u] += (float)v0[u];
            acc2[u] += (float)v1[u];
        }
    }
    if (i < end) {
        int s0 = csr[i];
        bf16x8 v0 = *(const bf16x8*)(feat + (size_t)s0 * 128 + c);
#pragma unroll
        for (int u = 0; u < 8; ++u) acc[u] += (float)v0[u];
    }
#pragma unroll
    for (int u = 0; u < 8; ++u) acc[u] += acc2[u];
#pragma unroll
    for (int m = 16; m <= 32; m <<= 1)
#pragma unroll
        for (int u = 0; u < 8; ++u) acc[u] += __shfl_xor(acc[u], m);
    if (q == 0) {
        int deg = end - beg;
        float inv = 1.0f / (float)(deg > 0 ? deg : 1);
        bf16x8 o;
#pragma unroll
        for (int u = 0; u < 8; ++u) o[u] = (bf16)(acc[u] * inv);
        *(bf16x8*)(agg + (size_t)node * 128 + c) = o;
    }
}

// Fused gemm1+gemm2: per 16-row tile, phase A computes h1 tile into LDS
// (relu([xb|agg1b]@Wt1^T + b1), Wt1 B-frags in registers), phase B reads
// h1 from LDS, MFMAs with Wt2 (re-read per tile; L1/L2-hot), then the wp-dot
// epilogue -> nodev {zp, zq, ps, qs}. No h1 materialization (saves 51 MB).
__global__ __launch_bounds__(256) void gemm12_kernel(
    const bf16* __restrict__ xb, const bf16* __restrict__ aggb,
    const bf16* __restrict__ Wt1, const bf16* __restrict__ Wt2,
    const float* __restrict__ b1, const float* __restrict__ b2,
    const float* __restrict__ wp, float4* __restrict__ nodev) {
    __shared__ bf16 hs[16][264];   // +8 pad: phase-B ds_read_b128 is 2-way (free)
    __shared__ float lp[4][16];
    __shared__ float lq[4][16];
    int w = threadIdx.x >> 6;
    int lane = threadIdx.x & 63;
    int r = lane & 15, quad = lane >> 4;
    int colbase = w * 64;

    // Wt1 B-frags resident in registers (128 VGPRs)
    bf16x8 bfr[4][8];
#pragma unroll
    for (int t = 0; t < 4; ++t)
#pragma unroll
        for (int kk = 0; kk < 8; ++kk)
            bfr[t][kk] = *(const bf16x8*)(Wt1 + (size_t)(colbase + t * 16 + r) * 256
                                          + kk * 32 + quad * 8);
    float bb1[4];
#pragma unroll
    for (int t = 0; t < 4; ++t) bb1[t] = b1[colbase + t * 16 + r];

    // gemm2 epilogue constants
    float bb2[4], wA[4], wB[4];
#pragma unroll
    for (int t = 0; t < 4; ++t) {
        int col = colbase + t * 16 + r;
        if (w < 2) {
            bb2[t] = 0.f;
            wA[t] = wp[col];
            wB[t] = wp[128 + col];
        } else {
            int c2 = col - 128;
            bb2[t] = b2[c2];
            wA[t] = wp[c2];
            wB[t] = wp[128 + c2];
        }
    }
    const bf16* wt2base = Wt2 + (size_t)(colbase + r) * 256 + quad * 8;

    for (int tile = blockIdx.x; tile < MTILES; tile += GEMM_GRID) {
        int m0 = tile * 16;
        int row = m0 + r;
        // ---- phase A: h1 tile ----
        {
            bf16x8 a[8];
#pragma unroll
            for (int kk = 0; kk < 4; ++kk)
                a[kk] = *(const bf16x8*)(xb + (size_t)row * 128 + kk * 32 + quad * 8);
#pragma unroll
            for (int kk = 4; kk < 8; ++kk)
                a[kk] = *(const bf16x8*)(aggb + (size_t)row * 128 + (kk - 4) * 32 + quad * 8);
            floatx4 acc[4];
#pragma unroll
            for (int t = 0; t < 4; ++t) acc[t] = (floatx4){0.f, 0.f, 0.f, 0.f};
#pragma unroll
            for (int kk = 0; kk < 8; ++kk)
#pragma unroll
                for (int t = 0; t < 4; ++t)
                    acc[t] = __builtin_amdgcn_mfma_f32_16x16x32_bf16(a[kk], bfr[t][kk],
                                                                     acc[t], 0, 0, 0);
#pragma unroll
            for (int t = 0; t < 4; ++t) {
                int col = colbase + t * 16 + r;
#pragma unroll
                for (int rr = 0; rr < 4; ++rr) {
                    float v = acc[t][rr] + bb1[t];
                    hs[quad * 4 + rr][col] = (bf16)(v > 0.f ? v : 0.f);
                }
            }
        }
        __syncthreads();
        // ---- phase B: gemm2 on LDS tile + wp-dot epilogue ----
        floatx4 acc2[4];
#pragma unroll
        for (int t = 0; t < 4; ++t) acc2[t] = (floatx4){0.f, 0.f, 0.f, 0.f};
#pragma unroll
        for (int kk = 0; kk < 8; ++kk) {
            bf16x8 a2 = *(const bf16x8*)(&hs[r][kk * 32 + quad * 8]);
#pragma unroll
            for (int t = 0; t < 4; ++t) {
                bf16x8 bw = *(const bf16x8*)(wt2base + (size_t)(t * 16) * 256 + kk * 32);
                acc2[t] = __builtin_amdgcn_mfma_f32_16x16x32_bf16(a2, bw, acc2[t], 0, 0, 0);
            }
        }
        float pacc[4], qacc[4];
#pragma unroll
        for (int rr = 0; rr < 4; ++rr) {
            float pr = 0.f, qr = 0.f;
#pragma unroll
            for (int t = 0; t < 4; ++t) {
                float v = acc2[t][rr] + bb2[t];
                pr += v * wA[t];
                qr += v * wB[t];
            }
            pacc[rr] = pr;
            qacc[rr] = qr;
        }
#pragma unroll
        for (int m = 1; m <= 8; m <<= 1) {
#pragma unroll
            for (int rr = 0; rr < 4; ++rr) {
                pacc[rr] += __shfl_xor(pacc[rr], m);
                qacc[rr] += __shfl_xor(qacc[rr], m);
            }
        }
        if (r == 0) {
#pragma unroll
            for (int rr = 0; rr < 4; ++rr) {
                lp[w][quad * 4 + rr] = pacc[rr];
                lq[w][quad * 4 + rr] = qacc[rr];
            }
        }
        __syncthreads();
        if (threadIdx.x < 16) {
            int rw = threadIdx.x;
            float4 o;
            o.x = lp[0][rw] + lp[1][rw];
            o.y = lq[0][rw] + lq[1][rw];
            o.z = lp[2][rw] + lp[3][rw];
            o.w = lq[2][rw] + lq[3][rw];
            nodev[m0 + rw] = o;
        }
        __syncthreads();   // protect hs + lp/lq before next tile
    }
}

// scalar gather: p[n] = ps[n] + mean(zp[src]); q likewise. nodev is 800 KB.
__global__ __launch_bounds__(256) void gather2_kernel(
    const float4* __restrict__ nodev, const int* __restrict__ rowstart,
    const int* __restrict__ csr, float* __restrict__ p, float* __restrict__ q) {
    int t = threadIdx.x;
    int node = blockIdx.x * 16 + (t >> 4);
    if (node >= NN) return;
    int l = t & 15;
    int beg = rowstart[node], end = rowstart[node + 1];
    float pz = 0.f, qz = 0.f;
    for (int i = beg + l; i < end; i += 16) {
        float4 v = nodev[csr[i]];
        pz += v.x;
        qz += v.y;
    }
#pragma unroll
    for (int m = 8; m >= 1; m >>= 1) {
        pz += __shfl_xor(pz, m);
        qz += __shfl_xor(qz, m);
    }
    if (l == 0) {
        int deg = end - beg;
        float inv = 1.0f / (float)(deg > 0 ? deg : 1);
        float4 me = nodev[node];
        p[node] = me.z + pz * inv;
        q[node] = me.w + qz * inv;
    }
}

__global__ __launch_bounds__(256) void score_kernel(
    const int* __restrict__ psrc, const int* __restrict__ pdst,
    const int* __restrict__ nsrc, const int* __restrict__ ndst,
    const float* __restrict__ p, const float* __restrict__ q,
    const float* __restrict__ bp, float* __restrict__ out) {
    int i = blockIdx.x * blockDim.x + threadIdx.x;
    float b = bp[0];
    if (i < EPOS) {
        out[i] = p[psrc[i]] + q[pdst[i]] + b;
    } else if (i < EPOS + ENEG) {
        int j = i - EPOS;
        out[i] = p[nsrc[j]] + q[ndst[j]] + b;
    }
}

extern "C" void kernel_launch(void* const* d_in, const int* in_sizes, int n_in,
                              void* d_out, int out_size, void* d_ws, size_t ws_size,
                              hipStream_t stream) {
    const float* x    = (const float*)d_in[0];
    const int*   msrc = (const int*)d_in[1];
    const int*   mdst = (const int*)d_in[2];
    const int*   psrc = (const int*)d_in[3];
    const int*   pdst = (const int*)d_in[4];
    const int*   nsrc = (const int*)d_in[5];
    const int*   ndst = (const int*)d_in[6];
    const float* W1s  = (const float*)d_in[7];
    const float* W1n  = (const float*)d_in[8];
    const float* b1   = (const float*)d_in[9];
    const float* W2s  = (const float*)d_in[10];
    const float* W2n  = (const float*)d_in[11];
    const float* b2   = (const float*)d_in[12];
    const float* wp   = (const float*)d_in[13];
    const float* bp   = (const float*)d_in[14];

    char* ws = (char*)d_ws;
    int*   boff     = (int*)ws + I_BOFF;
    int*   ccur     = (int*)ws + I_CCUR;
    int*   rowstart = (int*)ws + I_ROW;
    int*   csr      = (int*)ws + I_CSR;
    int*   hgrid    = (int*)ws + I_HG;
    unsigned* creg  = (unsigned*)(ws + B_CREG);
    bf16*  xb    = (bf16*)(ws + B_XB);
    bf16*  agg1b = (bf16*)(ws + B_AGG1);
    float4* nodev = (float4*)(ws + B_NV);
    bf16*  Wt1   = (bf16*)(ws + B_WT1);
    bf16*  Wt2   = (bf16*)(ws + B_WT2);
    float* p     = (float*)(ws + B_P);
    float* q     = (float*)(ws + B_Q);
    float* out   = (float*)d_out;

    convc_kernel<<<XCONV + 256 + CBLK, 256, 0, stream>>>(
        x, xb, W1s, W1n, W2n, W2s, Wt1, Wt2, mdst, hgrid);
    cscan_kernel<<<1, 256, 0, stream>>>(hgrid, boff, ccur);
    bin2_kernel<<<(EM + RPB - 1) / RPB, 256, 0, stream>>>(msrc, mdst, ccur, creg);
    binsort_kernel<<<NB, 256, 0, stream>>>(creg, boff, rowstart, csr);

    gather1_kernel<<<(NN + 3) / 4, 256, 0, stream>>>(xb, rowstart, csr, agg1b);
    gemm12_kernel<<<GEMM_GRID, 256, 0, stream>>>(xb, agg1b, Wt1, Wt2, b1, b2, wp, nodev);
    gather2_kernel<<<(NN + 15) / 16, 256, 0, stream>>>(nodev, rowstart, csr, p, q);
    score_kernel<<<(EPOS + ENEG + 255) / 256, 256, 0, stream>>>(
        psrc, pdst, nsrc, ndst, p, q, bp, out);
}

// Round 16
// 217.508 us; speedup vs baseline: 3.3867x; 1.0723x over previous
//
#include <hip/hip_runtime.h>

// GraphSAGE 2-layer + edge scorer, MI355X.
// R16: bucket-padded CSR. Fixed CAP=8192 slots per coarse bucket; bin
// atomically appends into region b*CAP (cursors memset to 0, 784 B) -- no
// global prefix scan needed because rowstart/rowend just point into the
// padded layout. Removes cscan launch + convc's hist section + one chain
// stage (bin fused into the conv grid, fully independent sections).
// gemm12 fusion reverted (R15: neutral, 172 VGPR) -> separate gemm1/gemm2.
// Kept: u32 records, 8-edge-ILP gather1, B-in-regs GEMMs, wp-dot commute
// (scalar gather2), mean(h1[src])@W2n == mean((h1@W2n)[src]).

#define NN 50000
#define EM 800000
#define EPOS 200000
#define ENEG 200000
#define NB 196            // coarse buckets: 196*256 >= NN
#define CAP 8192          // slots per bucket (max bucket ~4400 expected)
#define RPB 4096          // records per bin chunk
#define CBLK 196          // bin chunks: 196*4096 >= EM
#define MTILES 3125       // 50000 / 16 exactly
#define GEMM_GRID 512
#define XCONV 6250        // NN*128/4/256

typedef __bf16 bf16;
typedef bf16 bf16x4 __attribute__((ext_vector_type(4)));
typedef bf16 bf16x8 __attribute__((ext_vector_type(8)));
typedef float floatx4 __attribute__((ext_vector_type(4)));

// ---- workspace offsets ----
// int-word offsets:
#define I_CCUR 0             // 256 (memset 1 KB)
#define I_ROW  256           // 50176
#define I_REND 50432         // 50176 -> ends 100608
#define I_CSR  100608        // NB*CAP = 1,605,632 -> ends 1,706,240
// byte offsets (16B-aligned):
#define B_CREG 6824960       // NB*CAP*4 = 6,422,528 -> ends 13,247,488
#define B_XB   13247488      // 12.8 MB -> ends 26,047,488
#define B_AGG1 26047488      // 12.8 MB -> ends 38,847,488
#define B_H1   38847488      // 25.6 MB -> ends 64,447,488
#define B_NV   64447488      // 800 KB
#define B_WT1  65247488      // 128 KB
#define B_WT2  65378560      // 128 KB
#define B_P    65509632      // 200 KB
#define B_Q    65710336      // 200 KB -> ends ~65.9 MB

// one grid, three independent sections: x->bf16, weights->Wt1/Wt2, bin.
__global__ __launch_bounds__(256) void convbin_kernel(
    const float* __restrict__ x, bf16* __restrict__ xb,
    const float* __restrict__ W1s, const float* __restrict__ W1n,
    const float* __restrict__ W2n, const float* __restrict__ W2s,
    bf16* __restrict__ Wt1, bf16* __restrict__ Wt2,
    const int* __restrict__ msrc, const int* __restrict__ mdst,
    int* __restrict__ ccur, unsigned* __restrict__ creg) {
    if (blockIdx.x < XCONV) {
        int i = blockIdx.x * 256 + threadIdx.x;
        float4 v = ((const float4*)x)[i];
        bf16x4 o;
        o[0] = (bf16)v.x; o[1] = (bf16)v.y; o[2] = (bf16)v.z; o[3] = (bf16)v.w;
        *(bf16x4*)(xb + (size_t)i * 4) = o;
    } else if (blockIdx.x < XCONV + 256) {
        int i = (blockIdx.x - XCONV) * 256 + threadIdx.x;
        int n = i >> 8, k = i & 255;
        float w1 = (k < 128) ? W1s[k * 256 + n] : W1n[(k - 128) * 256 + n];
        Wt1[i] = (bf16)w1;
        float w2 = (n < 128) ? W2n[k * 128 + n] : W2s[k * 128 + (n - 128)];
        Wt2[i] = (bf16)w2;
    } else {
        // bin chunk: LDS-sort RPB edges by dst>>8, append bucket-grouped u32
        // records ((dst&255)<<16 | src) into fixed region b*CAP.
        __shared__ int hist[NB];
        __shared__ int cnt2[NB];
        __shared__ int goff[NB];
        __shared__ int base[256];
        __shared__ unsigned sorted[RPB];
        __shared__ unsigned char sbkt[RPB];
        int t = threadIdx.x;
        int cb = blockIdx.x - (XCONV + 256);
        int e0 = cb * RPB;
        int nrec = EM - e0; if (nrec > RPB) nrec = RPB;

        for (int i = t; i < NB; i += 256) { hist[i] = 0; cnt2[i] = 0; }
        __syncthreads();

        int myb[16];
        unsigned myrec[16];
#pragma unroll
        for (int j = 0; j < 16; ++j) {
            int idx = j * 256 + t;
            if (idx < nrec) {
                int s = msrc[e0 + idx], d = mdst[e0 + idx];
                myb[j] = d >> 8;
                myrec[j] = ((unsigned)(d & 255) << 16) | (unsigned)s;
                atomicAdd(&hist[myb[j]], 1);
            } else myb[j] = -1;
        }
        __syncthreads();

        base[t] = (t < NB) ? hist[t] : 0;
        __syncthreads();
        for (int o = 1; o < 256; o <<= 1) {
            int u = (t >= o) ? base[t - o] : 0;
            __syncthreads();
            base[t] += u;
            __syncthreads();
        }

        if (t < NB && hist[t] > 0)
            goff[t] = t * CAP + atomicAdd(&ccur[t], hist[t]);
#pragma unroll
        for (int j = 0; j < 16; ++j) {
            if (myb[j] >= 0) {
                int rk = atomicAdd(&cnt2[myb[j]], 1);
                int slot = base[myb[j]] - hist[myb[j]] + rk;
                sorted[slot] = myrec[j];
                sbkt[slot] = (unsigned char)myb[j];
            }
        }
        __syncthreads();

#pragma unroll
        for (int j = 0; j < 16; ++j) {
            int idx = j * 256 + t;
            if (idx < nrec) {
                int b = sbkt[idx];
                int exb = base[b] - hist[b];
                creg[(size_t)goff[b] + (idx - exb)] = sorted[idx];
            }
        }
    }
}

// one block per bucket: rowstart/rowend for its 256 nodes + csr placement,
// all within the bucket's exclusively-owned padded region [b*CAP, b*CAP+cnt).
__global__ __launch_bounds__(256) void binsort_kernel(
    const unsigned* __restrict__ creg, const int* __restrict__ ccur,
    int* __restrict__ rowstart, int* __restrict__ rowend,
    int* __restrict__ csr) {
    __shared__ int lcnt[256];
    __shared__ int sc[256];
    __shared__ int lcur[256];
    int b = blockIdx.x, t = threadIdx.x;
    int beg = b * CAP;
    int cnt = ccur[b];
    lcnt[t] = 0;
    __syncthreads();
    for (int i = t; i < cnt; i += 256)
        atomicAdd(&lcnt[(int)(creg[beg + i] >> 16) & 255], 1);
    __syncthreads();
    sc[t] = lcnt[t];
    __syncthreads();
    for (int o = 1; o < 256; o <<= 1) {
        int u = (t >= o) ? sc[t - o] : 0;
        __syncthreads();
        sc[t] += u;
        __syncthreads();
    }
    int node = b * 256 + t;
    if (node < NN) {
        rowstart[node] = beg + sc[t] - lcnt[t];
        rowend[node] = beg + sc[t];
    }
    lcur[t] = beg + sc[t] - lcnt[t];
    __syncthreads();
    for (int i = t; i < cnt; i += 256) {
        unsigned rec = creg[beg + i];
        int pos = atomicAdd(&lcur[(int)(rec >> 16) & 255], 1);
        csr[pos] = (int)(rec & 0xffffu);
    }
}

// one wave per node, 8 edges in flight (2 independent chains per quad-lane).
__global__ __launch_bounds__(256) void gather1_kernel(const bf16* __restrict__ feat,
                                                      const int* __restrict__ rowstart,
                                                      const int* __restrict__ rowend,
                                                      const int* __restrict__ csr,
                                                      bf16* __restrict__ agg) {
    int node = (blockIdx.x * 256 + threadIdx.x) >> 6;
    if (node >= NN) return;
    int lane = threadIdx.x & 63;
    int q = lane >> 4, r = lane & 15;
    int c = r * 8;
    int beg = rowstart[node], end = rowend[node];
    float acc[8] = {0.f, 0.f, 0.f, 0.f, 0.f, 0.f, 0.f, 0.f};
    float acc2[8] = {0.f, 0.f, 0.f, 0.f, 0.f, 0.f, 0.f, 0.f};
    int i = beg + q;
    for (; i + 4 < end; i += 8) {
        int s0 = csr[i], s1 = csr[i + 4];
        bf16x8 v0 = *(const bf16x8*)(feat + (size_t)s0 * 128 + c);
        bf16x8 v1 = *(const bf16x8*)(feat + (size_t)s1 * 128 + c);
#pragma unroll
        for (int u = 0; u < 8; ++u) {
            acc[u] += (float)v0[u];
            acc2[u] += (float)v1[u];
        }
    }
    if (i < end) {
        int s0 = csr[i];
        bf16x8 v0 = *(const bf16x8*)(feat + (size_t)s0 * 128 + c);
#pragma unroll
        for (int u = 0; u < 8; ++u) acc[u] += (float)v0[u];
    }
#pragma unroll
    for (int u = 0; u < 8; ++u) acc[u] += acc2[u];
#pragma unroll
    for (int m = 16; m <= 32; m <<= 1)
#pragma unroll
        for (int u = 0; u < 8; ++u) acc[u] += __shfl_xor(acc[u], m);
    if (q == 0) {
        int deg = end - beg;
        float inv = 1.0f / (float)(deg > 0 ? deg : 1);
        bf16x8 o;
#pragma unroll
        for (int u = 0; u < 8; ++u) o[u] = (bf16)(acc[u] * inv);
        *(bf16x8*)(agg + (size_t)node * 128 + c) = o;
    }
}

// h1 = relu([xb | agg1b] @ Wt1^T + b1) -> bf16. B in registers, A streamed.
__global__ __launch_bounds__(256) void gemm1_kernel(
    const bf16* __restrict__ xb, const bf16* __restrict__ aggb,
    const bf16* __restrict__ Wt, const float* __restrict__ b1,
    bf16* __restrict__ h1b) {
    int w = threadIdx.x >> 6;
    int lane = threadIdx.x & 63;
    int r = lane & 15, quad = lane >> 4;
    int colbase = w * 64;

    bf16x8 bfr[4][8];
#pragma unroll
    for (int t = 0; t < 4; ++t)
#pragma unroll
        for (int kk = 0; kk < 8; ++kk)
            bfr[t][kk] = *(const bf16x8*)(Wt + (size_t)(colbase + t * 16 + r) * 256
                                          + kk * 32 + quad * 8);
    float bb[4];
#pragma unroll
    for (int t = 0; t < 4; ++t) bb[t] = b1[colbase + t * 16 + r];

    for (int tile = blockIdx.x; tile < MTILES; tile += GEMM_GRID) {
        int m0 = tile * 16;
        int row = m0 + r;
        bf16x8 a[8];
#pragma unroll
        for (int kk = 0; kk < 4; ++kk)
            a[kk] = *(const bf16x8*)(xb + (size_t)row * 128 + kk * 32 + quad * 8);
#pragma unroll
        for (int kk = 4; kk < 8; ++kk)
            a[kk] = *(const bf16x8*)(aggb + (size_t)row * 128 + (kk - 4) * 32 + quad * 8);
        floatx4 acc[4];
#pragma unroll
        for (int t = 0; t < 4; ++t) acc[t] = (floatx4){0.f, 0.f, 0.f, 0.f};
#pragma unroll
        for (int kk = 0; kk < 8; ++kk)
#pragma unroll
            for (int t = 0; t < 4; ++t)
                acc[t] = __builtin_amdgcn_mfma_f32_16x16x32_bf16(a[kk], bfr[t][kk],
                                                                 acc[t], 0, 0, 0);
        int mb = m0 + quad * 4;
#pragma unroll
        for (int t = 0; t < 4; ++t) {
            int col = colbase + t * 16 + r;
#pragma unroll
            for (int rr = 0; rr < 4; ++rr) {
                float v = acc[t][rr] + bb[t];
                v = v > 0.f ? v : 0.f;
                h1b[(size_t)(mb + rr) * 256 + col] = (bf16)v;
            }
        }
    }
}

// Fused gemm2: nodev[n] = {zp, zq, ps, qs}; zp=(h1@W2n)[n].wp[:128] etc.
__global__ __launch_bounds__(256) void gemm2_kernel(
    const bf16* __restrict__ h1b, const bf16* __restrict__ Wt,
    const float* __restrict__ b2, const float* __restrict__ wp,
    float4* __restrict__ nodev) {
    __shared__ float lp[4][16];
    __shared__ float lq[4][16];
    int w = threadIdx.x >> 6;
    int lane = threadIdx.x & 63;
    int r = lane & 15, quad = lane >> 4;
    int colbase = w * 64;

    bf16x8 bfr[4][8];
#pragma unroll
    for (int t = 0; t < 4; ++t)
#pragma unroll
        for (int kk = 0; kk < 8; ++kk)
            bfr[t][kk] = *(const bf16x8*)(Wt + (size_t)(colbase + t * 16 + r) * 256
                                          + kk * 32 + quad * 8);
    float bb[4], wA[4], wB[4];
#pragma unroll
    for (int t = 0; t < 4; ++t) {
        int col = colbase + t * 16 + r;
        if (w < 2) {
            bb[t] = 0.f;
            wA[t] = wp[col];
            wB[t] = wp[128 + col];
        } else {
            int c2 = col - 128;
            bb[t] = b2[c2];
            wA[t] = wp[c2];
            wB[t] = wp[128 + c2];
        }
    }

    for (int tile = blockIdx.x; tile < MTILES; tile += GEMM_GRID) {
        int m0 = tile * 16;
        int row = m0 + r;
        bf16x8 a[8];
#pragma unroll
        for (int kk = 0; kk < 8; ++kk)
            a[kk] = *(const bf16x8*)(h1b + (size_t)row * 256 + kk * 32 + quad * 8);
        floatx4 acc[4];
#pragma unroll
        for (int t = 0; t < 4; ++t) acc[t] = (floatx4){0.f, 0.f, 0.f, 0.f};
#pragma unroll
        for (int kk = 0; kk < 8; ++kk)
#pragma unroll
            for (int t = 0; t < 4; ++t)
                acc[t] = __builtin_amdgcn_mfma_f32_16x16x32_bf16(a[kk], bfr[t][kk],
                                                                 acc[t], 0, 0, 0);
        float pacc[4], qacc[4];
#pragma unroll
        for (int rr = 0; rr < 4; ++rr) {
            float pr = 0.f, qr = 0.f;
#pragma unroll
            for (int t = 0; t < 4; ++t) {
                float v = acc[t][rr] + bb[t];
                pr += v * wA[t];
                qr += v * wB[t];
            }
            pacc[rr] = pr;
            qacc[rr] = qr;
        }
#pragma unroll
        for (int m = 1; m <= 8; m <<= 1) {
#pragma unroll
            for (int rr = 0; rr < 4; ++rr) {
                pacc[rr] += __shfl_xor(pacc[rr], m);
                qacc[rr] += __shfl_xor(qacc[rr], m);
            }
        }
        if (r == 0) {
#pragma unroll
            for (int rr = 0; rr < 4; ++rr) {
                lp[w][quad * 4 + rr] = pacc[rr];
                lq[w][quad * 4 + rr] = qacc[rr];
            }
        }
        __syncthreads();
        if (threadIdx.x < 16) {
            int rw = threadIdx.x;
            float4 o;
            o.x = lp[0][rw] + lp[1][rw];
            o.y = lq[0][rw] + lq[1][rw];
            o.z = lp[2][rw] + lp[3][rw];
            o.w = lq[2][rw] + lq[3][rw];
            nodev[m0 + rw] = o;
        }
        __syncthreads();
    }
}

// scalar gather: p[n] = ps[n] + mean(zp[src]); q likewise. nodev is 800 KB.
__global__ __launch_bounds__(256) void gather2_kernel(
    const float4* __restrict__ nodev, const int* __restrict__ rowstart,
    const int* __restrict__ rowend, const int* __restrict__ csr,
    float* __restrict__ p, float* __restrict__ q) {
    int t = threadIdx.x;
    int node = blockIdx.x * 16 + (t >> 4);
    if (node >= NN) return;
    int l = t & 15;
    int beg = rowstart[node], end = rowend[node];
    float pz = 0.f, qz = 0.f;
    for (int i = beg + l; i < end; i += 16) {
        float4 v = nodev[csr[i]];
        pz += v.x;
        qz += v.y;
    }
#pragma unroll
    for (int m = 8; m >= 1; m >>= 1) {
        pz += __shfl_xor(pz, m);
        qz += __shfl_xor(qz, m);
    }
    if (l == 0) {
        int deg = end - beg;
        float inv = 1.0f / (float)(deg > 0 ? deg : 1);
        float4 me = nodev[node];
        p[node] = me.z + pz * inv;
        q[node] = me.w + qz * inv;
    }
}

__global__ __launch_bounds__(256) void score_kernel(
    const int* __restrict__ psrc, const int* __restrict__ pdst,
    const int* __restrict__ nsrc, const int* __restrict__ ndst,
    const float* __restrict__ p, const float* __restrict__ q,
    const float* __restrict__ bp, float* __restrict__ out) {
    int i = blockIdx.x * blockDim.x + threadIdx.x;
    float b = bp[0];
    if (i < EPOS) {
        out[i] = p[psrc[i]] + q[pdst[i]] + b;
    } else if (i < EPOS + ENEG) {
        int j = i - EPOS;
        out[i] = p[nsrc[j]] + q[ndst[j]] + b;
    }
}

extern "C" void kernel_launch(void* const* d_in, const int* in_sizes, int n_in,
                              void* d_out, int out_size, void* d_ws, size_t ws_size,
                              hipStream_t stream) {
    const float* x    = (const float*)d_in[0];
    const int*   msrc = (const int*)d_in[1];
    const int*   mdst = (const int*)d_in[2];
    const int*   psrc = (const int*)d_in[3];
    const int*   pdst = (const int*)d_in[4];
    const int*   nsrc = (const int*)d_in[5];
    const int*   ndst = (const int*)d_in[6];
    const float* W1s  = (const float*)d_in[7];
    const float* W1n  = (const float*)d_in[8];
    const float* b1   = (const float*)d_in[9];
    const float* W2s  = (const float*)d_in[10];
    const float* W2n  = (const float*)d_in[11];
    const float* b2   = (const float*)d_in[12];
    const float* wp   = (const float*)d_in[13];
    const float* bp   = (const float*)d_in[14];

    char* ws = (char*)d_ws;
    int*   ccur     = (int*)ws + I_CCUR;
    int*   rowstart = (int*)ws + I_ROW;
    int*   rowend   = (int*)ws + I_REND;
    int*   csr      = (int*)ws + I_CSR;
    unsigned* creg  = (unsigned*)(ws + B_CREG);
    bf16*  xb    = (bf16*)(ws + B_XB);
    bf16*  agg1b = (bf16*)(ws + B_AGG1);
    bf16*  h1b   = (bf16*)(ws + B_H1);
    float4* nodev = (float4*)(ws + B_NV);
    bf16*  Wt1   = (bf16*)(ws + B_WT1);
    bf16*  Wt2   = (bf16*)(ws + B_WT2);
    float* p     = (float*)(ws + B_P);
    float* q     = (float*)(ws + B_Q);
    float* out   = (float*)d_out;

    hipMemsetAsync(ccur, 0, NB * sizeof(int), stream);

    convbin_kernel<<<XCONV + 256 + CBLK, 256, 0, stream>>>(
        x, xb, W1s, W1n, W2n, W2s, Wt1, Wt2, msrc, mdst, ccur, creg);
    binsort_kernel<<<NB, 256, 0, stream>>>(creg, ccur, rowstart, rowend, csr);

    gather1_kernel<<<(NN + 3) / 4, 256, 0, stream>>>(xb, rowstart, rowend, csr, agg1b);
    gemm1_kernel<<<GEMM_GRID, 256, 0, stream>>>(xb, agg1b, Wt1, b1, h1b);
    gemm2_kernel<<<GEMM_GRID, 256, 0, stream>>>(h1b, Wt2, b2, wp, nodev);
    gather2_kernel<<<(NN + 15) / 16, 256, 0, stream>>>(nodev, rowstart, rowend, csr, p, q);
    score_kernel<<<(EPOS + ENEG + 255) / 256, 256, 0, stream>>>(
        psrc, pdst, nsrc, ndst, p, q, bp, out);
}